// Round 5
// baseline (413.331 us; speedup 1.0000x reference)
//
#include <hip/hip_runtime.h>
#include <math.h>

// Problem constants (match reference)
#define N_NEU   8192
#define IN_SZ   512
#define OUT_SZ  512
#define N4      (N_NEU / 4)          // 2048 float4 col-quads per row of W_in/synapses
#define OUT4    (OUT_SZ / 4)         // 128 quads per W_out row
#define KPB     64                   // synapse k-rows per K1 block
#define WPB     4                    // W_in k-rows per K1 block
#define SYN_TILES (N_NEU / KPB)      // 128 -> grid (8,128) = 1024 blocks = 4/CU
#define K2_ROWS 32                   // rows per K2 block
#define K2_BLKS (N_NEU / K2_ROWS)    // 256 -> 1 block/CU (full chip)
constexpr float TAU_INV = 0.1f;
constexpr float G_GAIN  = 1.5f;

// ---------------------------------------------------------------------------
// K1: split-K GEMV, non-atomic partials. Block (bx,by) owns col-stripe bx
//     (1024 cols) and k-rows {64 synapse rows by*64.., 4 W_in rows by*4..}.
//     KPB=64 -> 1024 blocks = 4/CU = 4 waves/SIMD (vs 2 at KPB=128) for
//     latency hiding; un-confounded re-test of round 3 (atomics now gone).
//     Partials stored coalesced into P4[by][col4] (4 MB, L2/LLC-resident).
//     Block (0,0) zeroes out[0:512] for K2's atomics.
// grid = (8, 128), block = 256
// ---------------------------------------------------------------------------
__global__ __launch_bounds__(256)
void accum_kernel(const float* __restrict__ pot,
                  const float* __restrict__ inputs,
                  const float* __restrict__ synapses,
                  const float* __restrict__ W_in,
                  float4* __restrict__ P4,      // [128][2048] float4
                  float* __restrict__ out) {
    __shared__ float xs[KPB + WPB];
    const int bx = blockIdx.x, by = blockIdx.y;
    const int tid = threadIdx.x;
    const int k0 = by * KPB;       // synapse row base
    const int w0 = by * WPB;       // W_in row base
    if (tid < KPB)                xs[tid] = G_GAIN * tanhf(pot[k0 + tid]);
    else if (tid < KPB + WPB)     xs[tid] = inputs[w0 + (tid - KPB)];
    if (bx == 0 && by == 0 && tid < 128)
        ((float4*)out)[tid] = make_float4(0.f, 0.f, 0.f, 0.f);
    __syncthreads();

    const int col4 = bx * 256 + tid;
    const float4* Sp = (const float4*)synapses + (size_t)k0 * N4 + col4;
    const float4* Wp = (const float4*)W_in     + (size_t)w0 * N4 + col4;

    float4 acc = make_float4(0.f, 0.f, 0.f, 0.f);
#pragma unroll 8
    for (int i = 0; i < KPB; ++i) {
        float  s = xs[i];
        float4 m = Sp[(size_t)i * N4];
        acc.x = fmaf(s, m.x, acc.x);
        acc.y = fmaf(s, m.y, acc.y);
        acc.z = fmaf(s, m.z, acc.z);
        acc.w = fmaf(s, m.w, acc.w);
    }
#pragma unroll
    for (int i = 0; i < WPB; ++i) {
        float  s = xs[KPB + i];
        float4 m = Wp[(size_t)i * N4];
        acc.x = fmaf(s, m.x, acc.x);
        acc.y = fmaf(s, m.y, acc.y);
        acc.z = fmaf(s, m.z, acc.z);
        acc.w = fmaf(s, m.w, acc.w);
    }
    P4[(size_t)by * N4 + col4] = acc;          // coalesced private store
}

// ---------------------------------------------------------------------------
// K2: 256 blocks x 256 thr, 32 rows each (1 block/CU -> full chip, vs 128
//     blocks = half-idle chip in round 4).
//     Phase A: reduce 128 k-tile partials per row. Thread t: row r = t&31,
//       group q = t>>5 sums 16 tiles with 128B-coalesced reads; LDS combine
//       (8 groups) -> drive; pot_new -> out[512+], xs = tanh(pot_new).
//     Phase B: 32-row W_out gemv split across thread halves (h = t>>7 does
//       rows h*16..+16); LDS-combine; 128 threads atomicAdd out[0:512]
//       (131K fp32 atomics total — round-2-proven harmless level).
// grid = 256, block = 256
// ---------------------------------------------------------------------------
__global__ __launch_bounds__(256)
void finish_kernel(const float* __restrict__ pot,
                   const float* __restrict__ P,     // [128][8192] floats
                   const float* __restrict__ W_out,
                   float* __restrict__ out) {
    __shared__ float  red[256];
    __shared__ float  xs[K2_ROWS];
    __shared__ float4 hi[128];
    const int b = blockIdx.x;
    const int t = threadIdx.x;
    const int k0 = b * K2_ROWS;
    const int r = t & 31;           // row within tile
    const int q = t >> 5;           // group id: which 16 partial-tiles

    float s = 0.f;
#pragma unroll
    for (int p = 0; p < 16; ++p)
        s += P[(size_t)(q * 16 + p) * N_NEU + k0 + r];
    red[t] = s;
    __syncthreads();

    if (t < K2_ROWS) {
        float drive = red[t]       + red[32 + t]  + red[64 + t]  + red[96 + t]
                    + red[128 + t] + red[160 + t] + red[192 + t] + red[224 + t];
        float pv = pot[k0 + t];
        float pn = pv + (drive - pv) * TAU_INV;
        out[OUT_SZ + k0 + t] = pn;             // pot_new (exclusive rows)
        xs[t] = tanhf(pn);
    }
    __syncthreads();

    const int c4 = t & 127;         // output col4
    const int h  = t >> 7;          // row-half: 0 -> rows 0..15, 1 -> 16..31
    const float4* Wp = (const float4*)W_out + (size_t)(k0 + h * 16) * OUT4 + c4;
    float4 acc = make_float4(0.f, 0.f, 0.f, 0.f);
#pragma unroll
    for (int i = 0; i < 16; ++i) {
        float  sx = xs[h * 16 + i];
        float4 m  = Wp[(size_t)i * OUT4];
        acc.x = fmaf(sx, m.x, acc.x);
        acc.y = fmaf(sx, m.y, acc.y);
        acc.z = fmaf(sx, m.z, acc.z);
        acc.w = fmaf(sx, m.w, acc.w);
    }
    if (h == 1) hi[c4] = acc;
    __syncthreads();
    if (h == 0) {
        float4 o = hi[c4];
        acc.x += o.x; acc.y += o.y; acc.z += o.z; acc.w += o.w;
        float* op = out + (size_t)c4 * 4;
        atomicAdd(op + 0, acc.x);
        atomicAdd(op + 1, acc.y);
        atomicAdd(op + 2, acc.z);
        atomicAdd(op + 3, acc.w);
    }
}

// ---------------------------------------------------------------------------
extern "C" void kernel_launch(void* const* d_in, const int* in_sizes, int n_in,
                              void* d_out, int out_size, void* d_ws, size_t ws_size,
                              hipStream_t stream) {
    const float* inputs   = (const float*)d_in[0];   // [512]
    const float* pot      = (const float*)d_in[1];   // [8192]
    const float* W_in     = (const float*)d_in[2];   // [512, 8192]
    const float* synapses = (const float*)d_in[3];   // [8192, 8192]
    const float* W_out    = (const float*)d_in[4];   // [8192, 512]

    float* out = (float*)d_out;          // [0:512] output, [512:8704] pot_new
    float* P   = (float*)d_ws;           // [128][8192] partials = 4 MB

    // K1: 8 col-stripes x 128 k-tiles, non-atomic partials; zeroes out[0:512]
    accum_kernel<<<dim3(8, SYN_TILES), dim3(256), 0, stream>>>(
        pot, inputs, synapses, W_in, (float4*)P, out);

    // K2: 256 tiles of 32 rows: coalesced reduce + pot_new + split-row gemv
    finish_kernel<<<dim3(K2_BLKS), dim3(256), 0, stream>>>(
        pot, P, W_out, out);
}

// Round 6
// 387.304 us; speedup vs baseline: 1.0672x; 1.0672x over previous
//
#include <hip/hip_runtime.h>
#include <math.h>

// Problem constants (match reference)
#define N_NEU   8192
#define IN_SZ   512
#define OUT_SZ  512
#define N4      (N_NEU / 4)          // 2048 float4 col-quads per row of W_in/synapses
#define OUT4    (OUT_SZ / 4)         // 128 quads per W_out row
#define KPB     256                  // synapse k-rows per K1 block
#define WPB     16                   // W_in k-rows per K1 block
#define SYN_TILES (N_NEU / KPB)      // 32 -> grid (8,32) = 256 blocks = 1/CU
#define K2_ROWS 64                   // rows per K2 block
#define K2_BLKS (N_NEU / K2_ROWS)    // 128
constexpr float TAU_INV = 0.1f;
constexpr float G_GAIN  = 1.5f;

// ---------------------------------------------------------------------------
// K1: split-K GEMV, non-atomic partials. Block (bx,by) owns col-stripe bx
//     (1024 cols) and k-rows {256 synapse rows by*256.., 16 W_in rows by*16..}.
//     KPB=256 -> 256 blocks = 1 block/CU: single-variable test of the
//     stream-length/DRAM-page-locality trend (KPB 64->128 gained ~20-30 µs
//     twice; occupancy is not binding: per-CU demand ~25 GB/s, unroll-8
//     keeps ~9 KB/CU in flight > latency-BW product).
//     Partials stored coalesced into P4[by][col4] (1 MB, L2-resident).
//     Block (0,0) zeroes out[0:512] for K2's atomics.
// grid = (8, 32), block = 256
// ---------------------------------------------------------------------------
__global__ __launch_bounds__(256)
void accum_kernel(const float* __restrict__ pot,
                  const float* __restrict__ inputs,
                  const float* __restrict__ synapses,
                  const float* __restrict__ W_in,
                  float4* __restrict__ P4,      // [32][2048] float4
                  float* __restrict__ out) {
    __shared__ float xs[KPB + WPB];
    const int bx = blockIdx.x, by = blockIdx.y;
    const int tid = threadIdx.x;
    const int k0 = by * KPB;       // synapse row base
    const int w0 = by * WPB;       // W_in row base
    xs[tid] = G_GAIN * tanhf(pot[k0 + tid]);          // all 256 threads
    if (tid < WPB) xs[KPB + tid] = inputs[w0 + tid];  // 16 W_in rows
    if (bx == 0 && by == 0 && tid < 128)
        ((float4*)out)[tid] = make_float4(0.f, 0.f, 0.f, 0.f);
    __syncthreads();

    const int col4 = bx * 256 + tid;
    const float4* Sp = (const float4*)synapses + (size_t)k0 * N4 + col4;
    const float4* Wp = (const float4*)W_in     + (size_t)w0 * N4 + col4;

    float4 acc = make_float4(0.f, 0.f, 0.f, 0.f);
#pragma unroll 8
    for (int i = 0; i < KPB; ++i) {
        float  s = xs[i];
        float4 m = Sp[(size_t)i * N4];
        acc.x = fmaf(s, m.x, acc.x);
        acc.y = fmaf(s, m.y, acc.y);
        acc.z = fmaf(s, m.z, acc.z);
        acc.w = fmaf(s, m.w, acc.w);
    }
#pragma unroll
    for (int i = 0; i < WPB; ++i) {
        float  s = xs[KPB + i];
        float4 m = Wp[(size_t)i * N4];
        acc.x = fmaf(s, m.x, acc.x);
        acc.y = fmaf(s, m.y, acc.y);
        acc.z = fmaf(s, m.z, acc.z);
        acc.w = fmaf(s, m.w, acc.w);
    }
    P4[(size_t)by * N4 + col4] = acc;          // coalesced private store
}

// ---------------------------------------------------------------------------
// K2: 128 blocks x 256 thr, 64 rows each (round-4 structure, 32 tiles now).
//     Phase A: reduce the 32 k-tile partials per row. Wave q (t>>6) sums 8
//       tiles with coalesced 256B reads; LDS combine -> drive; pot_new ->
//       out[512+], xs = tanh(pot_new).
//     Phase B: 64-row W_out gemv split across thread halves (h = t>>7 does
//       rows h*32..+32); LDS-combine; 128 threads atomicAdd out[0:512]
//       (65K atomics — proven-cheap level).
// grid = 128, block = 256
// ---------------------------------------------------------------------------
__global__ __launch_bounds__(256)
void finish_kernel(const float* __restrict__ pot,
                   const float* __restrict__ P,     // [32][8192] floats
                   const float* __restrict__ W_out,
                   float* __restrict__ out) {
    __shared__ float  red[256];
    __shared__ float  xs[K2_ROWS];
    __shared__ float4 hi[128];
    const int b = blockIdx.x;
    const int t = threadIdx.x;
    const int k0 = b * K2_ROWS;
    const int r = t & 63;           // row within tile (= lane)
    const int q = t >> 6;           // wave id: which 8 partial-tiles

    float s = 0.f;
#pragma unroll
    for (int p = 0; p < 8; ++p)
        s += P[(size_t)(q * 8 + p) * N_NEU + k0 + r];
    red[t] = s;
    __syncthreads();

    if (t < K2_ROWS) {
        float drive = red[t] + red[64 + t] + red[128 + t] + red[192 + t];
        float pv = pot[k0 + t];
        float pn = pv + (drive - pv) * TAU_INV;
        out[OUT_SZ + k0 + t] = pn;             // pot_new (exclusive rows)
        xs[t] = tanhf(pn);
    }
    __syncthreads();

    const int c4 = t & 127;         // output col4
    const int h  = t >> 7;          // row-half: 0 -> rows 0..31, 1 -> 32..63
    const float4* Wp = (const float4*)W_out + (size_t)(k0 + h * 32) * OUT4 + c4;
    float4 acc = make_float4(0.f, 0.f, 0.f, 0.f);
#pragma unroll 8
    for (int i = 0; i < 32; ++i) {
        float  sx = xs[h * 32 + i];
        float4 m  = Wp[(size_t)i * OUT4];
        acc.x = fmaf(sx, m.x, acc.x);
        acc.y = fmaf(sx, m.y, acc.y);
        acc.z = fmaf(sx, m.z, acc.z);
        acc.w = fmaf(sx, m.w, acc.w);
    }
    if (h == 1) hi[c4] = acc;
    __syncthreads();
    if (h == 0) {
        float4 o = hi[c4];
        acc.x += o.x; acc.y += o.y; acc.z += o.z; acc.w += o.w;
        float* op = out + (size_t)c4 * 4;
        atomicAdd(op + 0, acc.x);
        atomicAdd(op + 1, acc.y);
        atomicAdd(op + 2, acc.z);
        atomicAdd(op + 3, acc.w);
    }
}

// ---------------------------------------------------------------------------
extern "C" void kernel_launch(void* const* d_in, const int* in_sizes, int n_in,
                              void* d_out, int out_size, void* d_ws, size_t ws_size,
                              hipStream_t stream) {
    const float* inputs   = (const float*)d_in[0];   // [512]
    const float* pot      = (const float*)d_in[1];   // [8192]
    const float* W_in     = (const float*)d_in[2];   // [512, 8192]
    const float* synapses = (const float*)d_in[3];   // [8192, 8192]
    const float* W_out    = (const float*)d_in[4];   // [8192, 512]

    float* out = (float*)d_out;          // [0:512] output, [512:8704] pot_new
    float* P   = (float*)d_ws;           // [32][8192] partials = 1 MB

    // K1: 8 col-stripes x 32 k-tiles, non-atomic partials; zeroes out[0:512]
    accum_kernel<<<dim3(8, SYN_TILES), dim3(256), 0, stream>>>(
        pot, inputs, synapses, W_in, (float4*)P, out);

    // K2: 128 tiles of 64 rows: coalesced reduce + pot_new + split-row gemv
    finish_kernel<<<dim3(K2_BLKS), dim3(256), 0, stream>>>(
        pot, P, W_out, out);
}